// Round 17
// baseline (55.387 us; speedup 1.0000x reference)
//
#include <hip/hip_runtime.h>
#include <hip/hip_bf16.h>
#include <hip/hip_fp16.h>

#define N_  4
#define C_  64
#define H_  28
#define W_  60
#define ZC_ 200
#define YC_ 8
#define XC_ 200
#define OUTC_ 128
#define KD_ 512            // C_*YC_
#define EPS_ 1e-6f
#define ZB 4               // z slices per block
#define XB 8               // x positions per block
#define NCOL 32            // ZB*XB columns per block

typedef __attribute__((ext_vector_type(8))) _Float16 half8;
typedef __attribute__((ext_vector_type(4))) float f32x4;
typedef __attribute__((ext_vector_type(4))) unsigned int u32x4;

// ---------------------------------------------------------------------------
// Prep: featH[n][h][w][c] = f16(img[n][c][h][w])  (channels-last, f16)
//       WbH[o][y*64+c]    = f16(W[o][c*8+y])      (y-major k, f16)
// ---------------------------------------------------------------------------
__global__ void gsvt_prep(const float* __restrict__ img,
                          const float* __restrict__ Wc,
                          __half* __restrict__ featH,
                          __half* __restrict__ WbH) {
    int tid = blockIdx.x * blockDim.x + threadIdx.x;
    int stride = gridDim.x * blockDim.x;
    const int totF = N_ * H_ * W_ * C_;       // 430080
    for (int i = tid; i < totF; i += stride) {
        int c  = i & 63;
        int hw = i >> 6;
        int w  = hw % W_;
        int nh = hw / W_;
        int h  = nh % H_;
        int n  = nh / H_;
        featH[i] = __float2half(img[((n * C_ + c) * H_ + h) * W_ + w]);
    }
    const int totW = OUTC_ * KD_;             // 65536
    for (int i = tid; i < totW; i += stride) {
        int k = i & (KD_ - 1);
        int o = i >> 9;
        int y = k >> 6;
        int c = k & 63;
        WbH[i] = __float2half(Wc[o * KD_ + c * YC_ + y]);
    }
}

// f16 accumulate of one corner (8 channels in u32x4), broadcast weight wp.
__device__ __forceinline__ void accq(__half2* n, const u32x4 V, const unsigned wp) {
    const __half2 w2 = *(const __half2*)&wp;
    unsigned vx = V.x, vy = V.y, vz = V.z, vw = V.w;
    n[0] = __hfma2(w2, *(const __half2*)&vx, n[0]);
    n[1] = __hfma2(w2, *(const __half2*)&vy, n[1]);
    n[2] = __hfma2(w2, *(const __half2*)&vz, n[2]);
    n[3] = __hfma2(w2, *(const __half2*)&vw, n[3]);
}

// corner addresses from a table entry (inactive -> all at base = hot line)
__device__ __forceinline__ void mkaddr(const uint4 T, const unsigned lb,
                                       unsigned& a0, unsigned& a1,
                                       unsigned& a2, unsigned& a3) {
    const bool act = (T.x | T.y) != 0u;
    const unsigned base = act ? (T.z + lb) : lb;
    const unsigned dxo  = act ? (T.w & 0xFFFFu) : 0u;
    const unsigned dyo  = act ? (T.w >> 16) : 0u;
    a0 = base; a1 = base + dxo; a2 = base + dyo; a3 = base + dyo + dxo;
}

// ===========================================================================
// Fused, software-pipelined gather: cam-pair granular 2-deep pipeline with
// tie-through vmcnt(8) waits (no sched fences) -> in-block f16 GEMM.
// Grid: (25, 50), block 256.  LDS = 48 KB.  launch_bounds(256,2).
// ===========================================================================
__global__ __launch_bounds__(256, 2) void gsvt_fusedP(
        const float* __restrict__ coords,        // (N, ZC, YC, XC, 3)
        const float* __restrict__ validm,        // (N, ZC, YC, XC)
        const __half* __restrict__ featH,        // (N, H, W, C) f16
        const __half* __restrict__ WbH,          // (OUTC, 512) f16, y-major k
        const float* __restrict__ bias,          // (OUTC)
        float* __restrict__ out)                 // (OUTC, ZC, XC)
{
    // tab entry (16B): x = w00|w01 (f16x2), y = w10|w11 (f16x2),
    //                  z = base byte offset, w = dxo | dyo<<16
    __shared__ uint4 tab[N_ * 256];              // 16 KB
    __shared__ unsigned short redB[64][NCOL][8]; // 32 KB (f16 payload)
    float (*ms)[4] = (float(*)[4])&redB[0][0][0];  // 4 KB alias (dead before redB)

    const int z0 = blockIdx.y * ZB;
    const int x0 = blockIdx.x * XB;
    const int t  = threadIdx.x;

    // ---- phase 0a ----
    const int p0   = t;
    const int y0_  = t >> 5;
    const int col0 = t & 31;
    const int zg   = z0 + (col0 >> 3);
    const int xg   = x0 + (col0 & 7);

    float gx[4], gy[4], gzv[4], mm[4];
    #pragma unroll
    for (int cam = 0; cam < N_; ++cam) {
        const int cb = ((cam * ZC_ + zg) * YC_ + y0_) * XC_ + xg;
        gx[cam]  = coords[cb * 3 + 0];
        gy[cam]  = coords[cb * 3 + 1];
        gzv[cam] = coords[cb * 3 + 2];
        mm[cam]  = validm[cb];
        ms[p0][cam] = mm[cam];
    }
    __syncthreads();

    // ---- phase 0b: f16 corner weights (mask, zw, 1/den folded) + offsets ----
    {
        const float inv = 1.0f / (ms[p0][0] + ms[p0][1] + ms[p0][2] + ms[p0][3] + EPS_);
        #pragma unroll
        for (int cam = 0; cam < N_; ++cam) {
            const float xf = ((gx[cam] + 1.0f) * (float)W_ - 1.0f) * 0.5f;
            const float yf = ((gy[cam] + 1.0f) * (float)H_ - 1.0f) * 0.5f;
            const float zf = gzv[cam] * 0.5f;
            const float x0f = floorf(xf), y0f = floorf(yf), z0f = floorf(zf);
            const float wx = xf - x0f, wy = yf - y0f, wz = zf - z0f;
            const int xi = (int)x0f, yi = (int)y0f, zi = (int)z0f;

            const float zw = (zi == 0) ? (1.f - wz) : ((zi == -1) ? wz : 0.f);
            const float s  = mm[cam] * zw * inv;

            const float wx0 = (xi >= 0 && xi < W_)         ? (1.f - wx) * s : 0.f;
            const float wx1 = (xi + 1 >= 0 && xi + 1 < W_) ? wx * s         : 0.f;
            const float wy0 = (yi >= 0 && yi < H_)         ? (1.f - wy)     : 0.f;
            const float wy1 = (yi + 1 >= 0 && yi + 1 < H_) ? wy             : 0.f;

            const unsigned h00 = __half_as_ushort(__float2half(wy0 * wx0));
            const unsigned h01 = __half_as_ushort(__float2half(wy0 * wx1));
            const unsigned h10 = __half_as_ushort(__float2half(wy1 * wx0));
            const unsigned h11 = __half_as_ushort(__float2half(wy1 * wx1));

            const int xc0 = min(max(xi, 0), W_ - 1);
            const int xc1 = min(max(xi + 1, 0), W_ - 1);
            const int yc0 = min(max(yi, 0), H_ - 1);
            const int yc1 = min(max(yi + 1, 0), H_ - 1);
            const unsigned base = (unsigned)((((cam * H_ + yc0) * W_) + xc0) * 128);
            const unsigned dxo  = (unsigned)((xc1 - xc0) * 128);          // 0 or 128
            const unsigned dyo  = (unsigned)((yc1 - yc0) * W_ * 128);     // 0 or 7680
            tab[cam * 256 + p0] = make_uint4(h00 | (h01 << 16), h10 | (h11 << 16),
                                             base, dxo | (dyo << 16));
        }
    }
    __syncthreads();

    // ---- sampling: pipelined, cam-pair granular ----
    const int grp   = t >> 3;        // column 0..31
    const int lane8 = t & 7;
    const unsigned lb = (unsigned)(lane8 << 4);
    const char* fb = (const char*)featH;

    #define ISSUE(V, A_) asm volatile("global_load_dwordx4 %0, %1, off" \
                                      : "=v"(V) : "v"(A_))
    // tie-through waits: RW operands force loads before / consumers after,
    // without fencing unrelated instructions (pipeline-friendly).
    #define WAIT8_8(a,b,c,d,e,f,g,h)                                        \
        asm volatile("s_waitcnt vmcnt(8)"                                    \
            : "+v"(a), "+v"(b), "+v"(c), "+v"(d),                            \
              "+v"(e), "+v"(f), "+v"(g), "+v"(h))
    #define WAIT8_0(a,b,c,d,e,f,g,h)                                        \
        asm volatile("s_waitcnt vmcnt(0)"                                    \
            : "+v"(a), "+v"(b), "+v"(c), "+v"(d),                            \
              "+v"(e), "+v"(f), "+v"(g), "+v"(h))

    #define BLO(u) (((u) & 0xFFFFu) | ((u) << 16))
    #define BHI(u) (((u) & 0xFFFF0000u) | ((u) >> 16))

    u32x4 A0v, A1v, A2v, A3v, B0v, B1v, B2v, B3v;   // cams 0,1 of current y
    u32x4 C0v, C1v, C2v, C3v, D0v, D1v, D2v, D3v;   // cams 2,3 of current y
    uint4 T0, T1, T2, T3;

    // prologue: tab(0) + issue cams 0,1 of y=0
    {
        T0 = tab[0 * 256 + grp];
        T1 = tab[1 * 256 + grp];
        T2 = tab[2 * 256 + grp];
        T3 = tab[3 * 256 + grp];
        unsigned a0,a1,a2,a3, b0,b1,b2,b3;
        mkaddr(T0, lb, a0,a1,a2,a3);
        mkaddr(T1, lb, b0,b1,b2,b3);
        ISSUE(A0v, fb + a0); ISSUE(A1v, fb + a1);
        ISSUE(A2v, fb + a2); ISSUE(A3v, fb + a3);
        ISSUE(B0v, fb + b0); ISSUE(B1v, fb + b1);
        ISSUE(B2v, fb + b2); ISSUE(B3v, fb + b3);
    }

    #define SBODY(Y, ISNEXT)                                                 \
    {                                                                        \
        /* issue cams 2,3 of this y */                                       \
        unsigned a0,a1,a2,a3, b0,b1,b2,b3;                                   \
        mkaddr(T2, lb, a0,a1,a2,a3);                                         \
        mkaddr(T3, lb, b0,b1,b2,b3);                                         \
        ISSUE(C0v, fb + a0); ISSUE(C1v, fb + a1);                            \
        ISSUE(C2v, fb + a2); ISSUE(C3v, fb + a3);                            \
        ISSUE(D0v, fb + b0); ISSUE(D1v, fb + b1);                            \
        ISSUE(D2v, fb + b2); ISSUE(D3v, fb + b3);                            \
        /* consume cams 0,1 (leaves cams 2,3 in flight) */                   \
        WAIT8_8(A0v,A1v,A2v,A3v, B0v,B1v,B2v,B3v);                           \
        __half2 z2 = __half2half2(__ushort_as_half(0));                      \
        __half2 num[4] = {z2, z2, z2, z2};                                   \
        accq(num, A0v, BLO(T0.x)); accq(num, A1v, BHI(T0.x));                \
        accq(num, A2v, BLO(T0.y)); accq(num, A3v, BHI(T0.y));                \
        accq(num, B0v, BLO(T1.x)); accq(num, B1v, BHI(T1.x));                \
        accq(num, B2v, BLO(T1.y)); accq(num, B3v, BHI(T1.y));                \
        const uint4 S2 = T2, S3 = T3;                                        \
        if (ISNEXT) {                                                        \
            /* tab(y+1) + issue its cams 0,1 (reuses A/B regs) */            \
            const int pn = ((Y) + 1) * 32 + grp;                             \
            T0 = tab[0 * 256 + pn]; T1 = tab[1 * 256 + pn];                  \
            T2 = tab[2 * 256 + pn]; T3 = tab[3 * 256 + pn];                  \
            unsigned c0,c1,c2,c3, d0,d1,d2,d3;                               \
            mkaddr(T0, lb, c0,c1,c2,c3);                                     \
            mkaddr(T1, lb, d0,d1,d2,d3);                                     \
            ISSUE(A0v, fb + c0); ISSUE(A1v, fb + c1);                        \
            ISSUE(A2v, fb + c2); ISSUE(A3v, fb + c3);                        \
            ISSUE(B0v, fb + d0); ISSUE(B1v, fb + d1);                        \
            ISSUE(B2v, fb + d2); ISSUE(B3v, fb + d3);                        \
            WAIT8_8(C0v,C1v,C2v,C3v, D0v,D1v,D2v,D3v);                       \
        } else {                                                             \
            WAIT8_0(C0v,C1v,C2v,C3v, D0v,D1v,D2v,D3v);                       \
        }                                                                    \
        accq(num, C0v, BLO(S2.x)); accq(num, C1v, BHI(S2.x));                \
        accq(num, C2v, BLO(S2.y)); accq(num, C3v, BHI(S2.y));                \
        accq(num, D0v, BLO(S3.x)); accq(num, D1v, BHI(S3.x));                \
        accq(num, D2v, BLO(S3.y)); accq(num, D3v, BHI(S3.y));                \
        const int kb   = (Y) * 8 + lane8;                                    \
        const int pcol = (grp & 16) | ((grp ^ kb) & 15);                     \
        unsigned n0 = *(unsigned*)&num[0], n1 = *(unsigned*)&num[1];         \
        unsigned n2 = *(unsigned*)&num[2], n3 = *(unsigned*)&num[3];         \
        *(uint4*)&redB[kb][pcol][0] = make_uint4(n0, n1, n2, n3);            \
    }

    SBODY(0, 1) SBODY(1, 1) SBODY(2, 1) SBODY(3, 1)
    SBODY(4, 1) SBODY(5, 1) SBODY(6, 1) SBODY(7, 0)

    #undef SBODY
    #undef ISSUE
    #undef WAIT8_8
    #undef WAIT8_0
    #undef BLO
    #undef BHI
    __syncthreads();

    // ---- GEMM: C[128,32] = WbH[128,512] * redB[512,32]  (f16 MFMA) ----
    const int wave = t >> 6;        // rows [wave*32, +32)
    const int lane = t & 63;
    const int q    = lane >> 4;
    const int l16  = lane & 15;

    f32x4 acc00 = {0.f,0.f,0.f,0.f}, acc01 = {0.f,0.f,0.f,0.f};
    f32x4 acc10 = {0.f,0.f,0.f,0.f}, acc11 = {0.f,0.f,0.f,0.f};
    const __half* wbase = WbH + (wave * 32 + l16) * KD_;

    #pragma unroll
    for (int ks = 0; ks < 16; ++ks) {
        const int kb = ks * 4 + q;
        const int xs = l16 ^ (kb & 15);
        const half8 Bf0 = *(const half8*)&redB[kb][xs][0];
        const half8 Bf1 = *(const half8*)&redB[kb][16 + xs][0];
        const half8 Af0 = *(const half8*)(wbase + ks * 32 + q * 8);
        const half8 Af1 = *(const half8*)(wbase + 16 * KD_ + ks * 32 + q * 8);
        acc00 = __builtin_amdgcn_mfma_f32_16x16x32_f16(Af0, Bf0, acc00, 0, 0, 0);
        acc01 = __builtin_amdgcn_mfma_f32_16x16x32_f16(Af0, Bf1, acc01, 0, 0, 0);
        acc10 = __builtin_amdgcn_mfma_f32_16x16x32_f16(Af1, Bf0, acc10, 0, 0, 0);
        acc11 = __builtin_amdgcn_mfma_f32_16x16x32_f16(Af1, Bf1, acc11, 0, 0, 0);
    }

    #pragma unroll
    for (int ct = 0; ct < 2; ++ct) {
        const int c2  = ct * 16 + l16;
        const int zz  = c2 >> 3;
        const int xl  = c2 & 7;
        const int ob  = (z0 + zz) * XC_ + x0 + xl;
        const f32x4 a0 = ct ? acc01 : acc00;
        const f32x4 a1 = ct ? acc11 : acc10;
        #pragma unroll
        for (int j = 0; j < 4; ++j) {
            const int o0 = wave * 32 + q * 4 + j;
            out[o0 * (ZC_ * XC_) + ob] = a0[j] + bias[o0];
            const int o1 = o0 + 16;
            out[o1 * (ZC_ * XC_) + ob] = a1[j] + bias[o1];
        }
    }
}

extern "C" void kernel_launch(void* const* d_in, const int* in_sizes, int n_in,
                              void* d_out, int out_size, void* d_ws, size_t ws_size,
                              hipStream_t stream) {
    const float* coords = (const float*)d_in[0];   // (1,4,200,8,200,3)
    const float* validm = (const float*)d_in[1];   // (1,4,200,8,200,1)
    const float* img    = (const float*)d_in[2];   // (1,4,64,28,60)
    const float* Wc     = (const float*)d_in[3];   // (128, 512)
    const float* bias   = (const float*)d_in[4];   // (128)
    float* out = (float*)d_out;                    // (1,1,128,200,200)

    __half* featH = (__half*)d_ws;                 // 430080 f16
    __half* WbH   = featH + (N_ * H_ * W_ * C_);   // 65536 f16

    gsvt_prep<<<512, 256, 0, stream>>>(img, Wc, featH, WbH);

    dim3 grid(XC_ / XB, ZC_ / ZB);   // (25, 50)
    gsvt_fusedP<<<grid, 256, 0, stream>>>(coords, validm, featH, WbH, bias, out);
}